// Round 19
// baseline (202.115 us; speedup 1.0000x reference)
//
#include <hip/hip_runtime.h>
#include <hip/hip_bf16.h>
#include <math.h>

// MoE: B=4,S=2048 -> N=8192 tokens, D=1024, DO=1024, E=20 experts, top-2.
// R19: R18 base + k_expert -> 256x256 tile WITH double-buffering (separates
// R13's confound: tile geometry was tested only with single-buffer). 512 thr,
// 8 waves (2Mx4N), wave-tile 128x64 (LDS reads/flop 1/32 -> 1/42.7), BK=64,
// dbuf 128KB LDS (1 block/CU), xb L2-refill 8->4 panels. K-ascending -> bit-exact.

#define N_TOK 8192
#define DIM   1024
#define DHID  256
#define DOUT  1024
#define NE    20
#define BM2   256
#define BN2   256
#define BK2   64
// sum_e ceil(cnt_e/256) <= 16384/256 + 20 = 84
#define MAX_TT 84

typedef __attribute__((ext_vector_type(8))) short bf16x8;
typedef __attribute__((ext_vector_type(4))) float f32x4;

__device__ __forceinline__ float gelu_erf(float v) {
    return 0.5f * v * (1.0f + erff(v * 0.70710678118654752f));
}

__device__ __forceinline__ ushort f2b(float f) {
  union { float f; uint u; } c; c.f = f;
  uint r = (c.u + 0x7FFFu + ((c.u >> 16) & 1u)) >> 16;  // RNE
  return (ushort)r;
}

__device__ __forceinline__ float b2f(ushort u) {
  union { uint u; float f; } c; c.u = ((uint)u) << 16;
  return c.f;
}

// ============ k_front: [0,512) gate GEMM | [512,5632) We->bf16T | [5632,7680) x->bf16
__global__ __launch_bounds__(256) void k_front(
    const float* __restrict__ x, const float* __restrict__ wg1,
    const float* __restrict__ bg1, float* __restrict__ h,
    const float* __restrict__ We, ushort* __restrict__ weT,
    ushort* __restrict__ xb) {
  __shared__ __align__(1024) char smem[32768];
  const int bid = blockIdx.x;
  const int t = threadIdx.x;

  if (bid < 512) {
    // ---- gating GEMM: h = gelu(x @ wg1 + bg1), 64x64 tile, fp32, dbuf (R18) ----
    const int ty = t >> 4, tx = t & 15;
    const int m0 = (bid >> 2) * 64;
    const int c0 = (bid & 3) * 64;

    const float* xsrc[2];
    const float* wsrc[2];
    int dsto[4];
#pragma unroll
    for (int l = 0; l < 2; ++l) {
      int i = t + l * 256;
      int row = i >> 3, seg = i & 7;
      xsrc[l] = x + (size_t)(m0 + row) * DIM + ((seg ^ ((row >> 2) & 7)) << 2);
      dsto[l] = i * 16;
      int kk = i >> 4, sg2 = i & 15;
      wsrc[l] = wg1 + (size_t)kk * DHID + c0 + sg2 * 4;
      dsto[2 + l] = 8192 + i * 16;
    }

#pragma unroll
    for (int l = 0; l < 2; ++l)
      __builtin_amdgcn_global_load_lds(xsrc[l], (float*)(smem + dsto[l]), 16, 0, 0);
#pragma unroll
    for (int l = 0; l < 2; ++l)
      __builtin_amdgcn_global_load_lds(wsrc[l], (float*)(smem + dsto[2 + l]), 16, 0, 0);

    float acc[4][4] = {};
    int cur = 0;
    for (int k0 = 0; k0 < DIM; k0 += 32) {
      __syncthreads();
      if (k0 + 32 < DIM) {
        const int koff = k0 + 32;
        const int dsh = (cur ^ 1) ? 16384 : 0;
#pragma unroll
        for (int l = 0; l < 2; ++l)
          __builtin_amdgcn_global_load_lds(xsrc[l] + koff,
                                           (float*)(smem + dsh + dsto[l]), 16, 0, 0);
#pragma unroll
        for (int l = 0; l < 2; ++l)
          __builtin_amdgcn_global_load_lds(wsrc[l] + (size_t)koff * DHID,
                                           (float*)(smem + dsh + dsto[2 + l]), 16, 0, 0);
      }
      const char* XsB = smem + (cur ? 16384 : 0);
      const float (*Ws)[64] = (const float(*)[64])(XsB + 8192);
#pragma unroll
      for (int q = 0; q < 8; ++q) {
        float4 a[4];
        const int qs = (q ^ (ty & 7)) << 4;
#pragma unroll
        for (int i = 0; i < 4; ++i)
          a[i] = *(const float4*)(XsB + (ty * 4 + i) * 128 + qs);
#pragma unroll
        for (int u = 0; u < 4; ++u) {
          float4 b = *(const float4*)&Ws[q * 4 + u][tx * 4];
#pragma unroll
          for (int i = 0; i < 4; ++i) {
            float av = reinterpret_cast<const float*>(&a[i])[u];
            acc[i][0] += av * b.x;
            acc[i][1] += av * b.y;
            acc[i][2] += av * b.z;
            acc[i][3] += av * b.w;
          }
        }
      }
      cur ^= 1;
    }
#pragma unroll
    for (int i = 0; i < 4; ++i) {
      int row = m0 + ty * 4 + i;
      int col = c0 + tx * 4;
      float4 o;
      o.x = gelu_erf(acc[i][0] + bg1[col + 0]);
      o.y = gelu_erf(acc[i][1] + bg1[col + 1]);
      o.z = gelu_erf(acc[i][2] + bg1[col + 2]);
      o.w = gelu_erf(acc[i][3] + bg1[col + 3]);
      *(float4*)&h[(size_t)row * DHID + col] = o;
    }
  } else if (bid < 5632) {
    // ---- We [e][k][n] fp32 -> weT [e][n][k] bf16 (R15 conflict-free) ----
    ushort* Ts = (ushort*)smem;                            // 8192 B
    const int b = bid - 512;
    const int e = b >> 8, rem = b & 255;
    const int k0 = (rem >> 4) * 64;
    const int n0 = (rem & 15) * 64;
    const float* src = We + ((size_t)e << 20);
    const int m = t & 15;
    const int xk = (m & 7) << 3;
#pragma unroll
    for (int it = 0; it < 4; ++it) {
      int kk = it * 16 + (t >> 4);
      int nn = m * 4;
      float4 v = *(const float4*)(src + (size_t)(k0 + kk) * DOUT + n0 + nn);
      int col = kk ^ xk;
      Ts[(nn + 0) * 64 + col] = f2b(v.x);
      Ts[(nn + 1) * 64 + col] = f2b(v.y);
      Ts[(nn + 2) * 64 + col] = f2b(v.z);
      Ts[(nn + 3) * 64 + col] = f2b(v.w);
    }
    __syncthreads();
    ushort* dst = weT + ((size_t)e << 20);
#pragma unroll
    for (int it = 0; it < 2; ++it) {
      int nn = it * 32 + (t >> 3);
      int ks = (t & 7) * 8;
      int cs = ks ^ (((nn >> 2) & 7) << 3);
      uint4 v = *(const uint4*)&Ts[nn * 64 + cs];
      *(uint4*)(dst + (size_t)(n0 + nn) * DIM + k0 + ks) = v;
    }
  } else {
    // ---- x fp32 -> bf16, 16 elems/thread ----
    const size_t i0 = (((size_t)(bid - 5632)) * 256 + t) * 16;
    ushort o[16];
#pragma unroll
    for (int j = 0; j < 4; ++j) {
      float4 v = *(const float4*)(x + i0 + j * 4);
      o[j * 4 + 0] = f2b(v.x); o[j * 4 + 1] = f2b(v.y);
      o[j * 4 + 2] = f2b(v.z); o[j * 4 + 3] = f2b(v.w);
    }
    *(uint4*)(xb + i0)     = *(const uint4*)&o[0];
    *(uint4*)(xb + i0 + 8) = *(const uint4*)&o[8];
  }
}

// -------- router: logits = (h@wg2+bg2)[:, :20], softmax, top-2, counts -------
__global__ __launch_bounds__(64) void k_router(
    const float* __restrict__ h, const float* __restrict__ wg2,
    const float* __restrict__ bg2, int* __restrict__ tokexp,
    float* __restrict__ tokgate, int* __restrict__ counts) {
  __shared__ float swg[DHID * NE];   // 20 KB
  __shared__ int hist[NE];
  const int t = threadIdx.x;
  if (t < NE) hist[t] = 0;
  for (int i = t; i < DHID * NE; i += 64) {
    int k = i / NE, j = i - k * NE;
    swg[i] = wg2[(size_t)k * (2 * NE) + j];
  }
  __syncthreads();
  const int n = blockIdx.x * 64 + t;
  float s[NE];
#pragma unroll
  for (int j = 0; j < NE; ++j) s[j] = bg2[j];
  const float* hr = h + (size_t)n * DHID;
  for (int k = 0; k < DHID; k += 4) {
    float4 hv = *(const float4*)(hr + k);
#pragma unroll
    for (int u = 0; u < 4; ++u) {
      float hvu = reinterpret_cast<const float*>(&hv)[u];
      const float4* wrow = (const float4*)&swg[(k + u) * NE];
      float wl[NE];
      *(float4*)&wl[0]  = wrow[0];
      *(float4*)&wl[4]  = wrow[1];
      *(float4*)&wl[8]  = wrow[2];
      *(float4*)&wl[12] = wrow[3];
      *(float4*)&wl[16] = wrow[4];
#pragma unroll
      for (int j = 0; j < NE; ++j) s[j] += hvu * wl[j];
    }
  }
  float m = s[0];
#pragma unroll
  for (int j = 1; j < NE; ++j) m = fmaxf(m, s[j]);
  float sum = 0.0f;
#pragma unroll
  for (int j = 0; j < NE; ++j) { s[j] = expf(s[j] - m); sum += s[j]; }
  float inv = 1.0f / sum;
#pragma unroll
  for (int j = 0; j < NE; ++j) s[j] *= inv;
  int j0 = 0; float v0 = s[0];
#pragma unroll
  for (int j = 1; j < NE; ++j) if (s[j] > v0) { v0 = s[j]; j0 = j; }
  int j1 = -1; float v1 = -1.0f;
#pragma unroll
  for (int j = 0; j < NE; ++j)
    if (j != j0 && s[j] > v1) { v1 = s[j]; j1 = j; }
  tokexp[2 * n + 0] = j0;  tokgate[2 * n + 0] = v0;
  tokexp[2 * n + 1] = j1;  tokgate[2 * n + 1] = v1;
  atomicAdd(&hist[j0], 1);
  atomicAdd(&hist[j1], 1);
  __syncthreads();
  if (t < NE) atomicAdd(&counts[t], hist[t]);
}

// ------ scatter: LDS-aggregated cursor claim (R16) ---------------------------
__global__ __launch_bounds__(256) void k_scatter(
    const int* __restrict__ tokexp, const float* __restrict__ tokgate,
    const int* __restrict__ counts, int* __restrict__ zcur,
    int* __restrict__ perm, float* __restrict__ pgate, int* __restrict__ inv) {
  __shared__ int soff[NE], lcnt[NE], lbase[NE];
  const int t = threadIdx.x;
  if (t < NE) lcnt[t] = 0;
  if (t < 64) {
    int c = (t < NE) ? counts[t] : 0;
    int cs = c;
    for (int d = 1; d < 64; d <<= 1) {
      int u = __shfl_up(cs, d); if (t >= d) cs += u;
    }
    if (t < NE) soff[t] = cs - c;
  }
  __syncthreads();
  const int n = blockIdx.x * 256 + t;
  const int e0 = tokexp[2 * n + 0];
  const int e1 = tokexp[2 * n + 1];
  const int r0 = atomicAdd(&lcnt[e0], 1);
  const int r1 = atomicAdd(&lcnt[e1], 1);
  __syncthreads();
  if (t < NE) lbase[t] = atomicAdd(&zcur[t], lcnt[t]);
  __syncthreads();
  {
    int pos = soff[e0] + lbase[e0] + r0;
    perm[pos] = n;
    pgate[pos] = tokgate[2 * n + 0];
    inv[2 * n + 0] = pos;
  }
  {
    int pos = soff[e1] + lbase[e1] + r1;
    perm[pos] = n;
    pgate[pos] = tokgate[2 * n + 1];
    inv[2 * n + 1] = pos;
  }
}

// ------ grouped expert GEMM (bf16 MFMA): contrib[pos] = g*(x@We[e]+be[e]) ----
// 256x256 tile, BK=64, 512 thr / 8 waves (2Mx4N), wave-tile 128x64, DOUBLE-
// buffered 128KB LDS: sync -> STAGE(next) -> compute(cur). In-block prefix.
__global__ __launch_bounds__(512) void k_expert(
    const ushort* __restrict__ xb, const ushort* __restrict__ weT,
    const float* __restrict__ be, const int* __restrict__ perm,
    const float* __restrict__ pgate, const int* __restrict__ counts,
    ushort* __restrict__ contrib) {
  // exact bijective XCD chunk: 336 blocks = 8 XCDs x 42
  const int lin = blockIdx.x + blockIdx.y * MAX_TT;
  const int wgid = (lin & 7) * 42 + (lin >> 3);
  const int rt = wgid >> 2, pn = wgid & 3;

  // layout: stok[256]@0 | sgate[256]@1024 | A0@2048 B0@34816 | A1@67584
  //         B1@100352 | end 133120
  __shared__ __align__(1024) char smem[133120];
  int*    stok  = (int*)smem;
  float*  sgate = (float*)(smem + 1024);
  ushort* As0   = (ushort*)(smem + 2048);
  ushort* Bs0   = (ushort*)(smem + 34816);
  __shared__ int tinfo[3];

  const int t = threadIdx.x;
  if (t < 64) {
    if (t == 0) tinfo[0] = -1;
    int c = (t < NE) ? counts[t] : 0;
    int nt = (c + BM2 - 1) >> 8;
    int cs = c, ts = nt;
    for (int d = 1; d < 64; d <<= 1) {
      int u = __shfl_up(cs, d); if (t >= d) cs += u;
      int v = __shfl_up(ts, d); if (t >= d) ts += v;
    }
    int coff = cs - c, toff = ts - nt;
    if (t < NE && rt >= toff && rt < toff + nt) {
      int i = rt - toff;
      tinfo[0] = t;
      tinfo[1] = coff + i * BM2;
      tinfo[2] = min(BM2, c - i * BM2);
    }
  }
  __syncthreads();
  if (tinfo[0] < 0) return;
  const int e = tinfo[0], rs = tinfo[1], cnt = tinfo[2];
  const int c0 = pn * BN2;

  if (t < BM2) {
    int r = (t < cnt) ? rs + t : rs;
    stok[t]  = perm[r];
    sgate[t] = (t < cnt) ? pgate[rs + t] : 0.0f;
  }
  __syncthreads();
  const int lane = t & 63, w = t >> 6;          // 8 waves
  const int wr = w >> 2, wc = w & 3;            // 2M x 4N wave grid
  const int lr = lane & 15, hi = lane >> 4;
  const int srow = lane >> 3, sseg = lane & 7;

  const ushort* asrc[4];
  const ushort* bsrc[4];
  ushort* adst[4];
  ushort* bdst[4];
#pragma unroll
  for (int l = 0; l < 4; ++l) {
    int r = w * 32 + l * 8 + srow;              // 0..255
    asrc[l] = xb + (size_t)stok[r] * DIM + ((sseg ^ (r & 7)) << 3);
    adst[l] = As0 + (w * 32 + l * 8) * BK2;
    bsrc[l] = weT + ((size_t)e << 20) + (size_t)(c0 + r) * DIM + ((sseg ^ (r & 7)) << 3);
    bdst[l] = Bs0 + (w * 32 + l * 8) * BK2;
  }

  f32x4 acc[8][4] = {};

  // prologue: stage k=0 into buf0
#pragma unroll
  for (int l = 0; l < 4; ++l)
    __builtin_amdgcn_global_load_lds(asrc[l], adst[l], 16, 0, 0);
#pragma unroll
  for (int l = 0; l < 4; ++l)
    __builtin_amdgcn_global_load_lds(bsrc[l], bdst[l], 16, 0, 0);

  int cur = 0;
  for (int k0 = 0; k0 < DIM; k0 += BK2) {
    __syncthreads();   // buf[cur] staged; prev readers of buf[nxt] done
    const int nxt = cur ^ 1;
    if (k0 + BK2 < DIM) {
      const int koff = k0 + BK2;
      const int dsh = nxt ? 32768 : 0;          // ushort offset: 64 KB
#pragma unroll
      for (int l = 0; l < 4; ++l)
        __builtin_amdgcn_global_load_lds(asrc[l] + koff, adst[l] + dsh, 16, 0, 0);
#pragma unroll
      for (int l = 0; l < 4; ++l)
        __builtin_amdgcn_global_load_lds(bsrc[l] + koff, bdst[l] + dsh, 16, 0, 0);
    }
    const char* Ab = (const char*)smem + 2048 + (cur ? 65536 : 0);
    const char* Bb = Ab + 32768;
#pragma unroll
    for (int ks = 0; ks < 2; ++ks) {
      const int kb = ks * 64 + hi * 16;
      bf16x8 af[8], bfr[4];
#pragma unroll
      for (int mi = 0; mi < 8; ++mi) {
        int r = wr * 128 + mi * 16 + lr;
        af[mi] = *(const bf16x8*)(Ab + r * 128 + (kb ^ ((r & 7) << 4)));
      }
#pragma unroll
      for (int ni = 0; ni < 4; ++ni) {
        int n = wc * 64 + ni * 16 + lr;
        bfr[ni] = *(const bf16x8*)(Bb + n * 128 + (kb ^ ((n & 7) << 4)));
      }
#pragma unroll
      for (int mi = 0; mi < 8; ++mi)
#pragma unroll
        for (int ni = 0; ni < 4; ++ni)
          acc[mi][ni] = __builtin_amdgcn_mfma_f32_16x16x32_bf16(
              af[mi], bfr[ni], acc[mi][ni], 0, 0, 0);
    }
    cur = nxt;
  }
  __syncthreads();

  // ---- epilogue: 4 passes x 32 rows, per-wave Ep[32][72] slab (reuses bufs) ----
  ushort (*Ep)[72] = (ushort(*)[72])(smem + 2048 + w * 4608);  // 8*4608=36864B
  float bcol[4];
#pragma unroll
  for (int ni = 0; ni < 4; ++ni)
    bcol[ni] = be[(size_t)e * DOUT + c0 + wc * 64 + ni * 16 + lr];
#pragma unroll
  for (int p = 0; p < 4; ++p) {
#pragma unroll
    for (int m2 = 0; m2 < 2; ++m2) {
      int mi = p * 2 + m2;
#pragma unroll
      for (int rr = 0; rr < 4; ++rr) {
        int rowl = m2 * 16 + hi * 4 + rr;   // C/D: col=lane&15, row=(lane>>4)*4+reg
        float g = sgate[wr * 128 + p * 32 + rowl];
#pragma unroll
        for (int ni = 0; ni < 4; ++ni)
          Ep[rowl][ni * 16 + lr] = f2b(g * (acc[mi][ni][rr] + bcol[ni]));
      }
    }
    __syncthreads();
#pragma unroll
    for (int it = 0; it < 4; ++it) {
      int rowl = it * 8 + (lane >> 3);
      int slot = wr * 128 + p * 32 + rowl;
      if (slot < cnt) {
        uint4 v = *(const uint4*)&Ep[rowl][(lane & 7) * 8];
        *(uint4*)(contrib + (size_t)(rs + slot) * DOUT + c0 + wc * 64 + (lane & 7) * 8) = v;
      }
    }
    __syncthreads();
  }
}

// --------- reduce: y[n] = contrib[inv[2n]] + contrib[inv[2n+1]] --------------
__global__ __launch_bounds__(256) void k_reduce(
    const ushort* __restrict__ contrib, const int* __restrict__ inv,
    float* __restrict__ y) {
  const int t = threadIdx.x;
  const int n = blockIdx.x * 2 + (t >> 7);
  const int c = (t & 127) * 8;
  const int p0 = inv[2 * n], p1 = inv[2 * n + 1];
  uint4 a = *(const uint4*)(contrib + (size_t)p0 * DOUT + c);
  uint4 b = *(const uint4*)(contrib + (size_t)p1 * DOUT + c);
  const ushort* ua = (const ushort*)&a;
  const ushort* ub = (const ushort*)&b;
  float4 o0, o1;
  o0.x = b2f(ua[0]) + b2f(ub[0]);
  o0.y = b2f(ua[1]) + b2f(ub[1]);
  o0.z = b2f(ua[2]) + b2f(ub[2]);
  o0.w = b2f(ua[3]) + b2f(ub[3]);
  o1.x = b2f(ua[4]) + b2f(ub[4]);
  o1.y = b2f(ua[5]) + b2f(ub[5]);
  o1.z = b2f(ua[6]) + b2f(ub[6]);
  o1.w = b2f(ua[7]) + b2f(ub[7]);
  float* yr = y + (size_t)n * DOUT + c;
  *(float4*)yr = o0;
  *(float4*)(yr + 4) = o1;
}

extern "C" void kernel_launch(void* const* d_in, const int* in_sizes, int n_in,
                              void* d_out, int out_size, void* d_ws, size_t ws_size,
                              hipStream_t stream) {
  (void)in_sizes; (void)n_in; (void)ws_size; (void)out_size;
  const float* x   = (const float*)d_in[0];
  const float* wg1 = (const float*)d_in[1];
  const float* bg1 = (const float*)d_in[2];
  const float* wg2 = (const float*)d_in[3];
  const float* bg2 = (const float*)d_in[4];
  const float* We  = (const float*)d_in[5];
  const float* be  = (const float*)d_in[6];
  float* y = (float*)d_out;

  char* ws = (char*)d_ws;
  float*  h       = (float*)ws;                                      // 8 MB
  ushort* xb      = (ushort*)(ws + (size_t)N_TOK * DHID * 4);        // 16 MB
  ushort* weT     = (ushort*)((char*)xb + (size_t)N_TOK * DIM * 2);  // 40 MB
  ushort* contrib = (ushort*)((char*)weT + (size_t)NE * DIM * DOUT * 2);  // 32 MB
  char*   ctrl    = (char*)contrib + (size_t)2 * N_TOK * DOUT * 2;
  int*   counts  = (int*)ctrl;
  int*   zcur    = counts + 64;                      // zeroed by memset below
  int*   tokexp  = counts + 128;
  float* tokgate = (float*)(tokexp + 2 * N_TOK);
  int*   perm    = (int*)(tokgate + 2 * N_TOK);
  float* pgate   = (float*)(perm + 2 * N_TOK);
  int*   inv     = (int*)(pgate + 2 * N_TOK);

  hipMemsetAsync(counts, 0, 128 * sizeof(int), stream);

  k_front<<<dim3(512 + 5120 + 2048), 256, 0, stream>>>(x, wg1, bg1, h, We, weT, xb);
  k_router<<<dim3(N_TOK / 64), 64, 0, stream>>>(h, wg2, bg2, tokexp, tokgate, counts);
  k_scatter<<<dim3(N_TOK / 256), 256, 0, stream>>>(tokexp, tokgate, counts, zcur,
                                                   perm, pgate, inv);
  k_expert<<<dim3(MAX_TT, DOUT / BN2), 512, 0, stream>>>(
      xb, weT, be, perm, pgate, counts, contrib);
  k_reduce<<<dim3(N_TOK / 2), 256, 0, stream>>>(contrib, inv, y);
}

// Round 20
// 184.683 us; speedup vs baseline: 1.0944x; 1.0944x over previous
//
#include <hip/hip_runtime.h>
#include <hip/hip_bf16.h>
#include <math.h>

// MoE: B=4,S=2048 -> N=8192 tokens, D=1024, DO=1024, E=20 experts, top-2.
// R20: exact restore of R18 (best, 186.09us). R19's 256x256+dbuf expert
// regressed (202us) -> 128x128 dbuf expert confirmed optimal for this scale.
// Pipeline: k_front (fp32 gate GEMM 64x64 dbuf + We->bf16T transpose + x->bf16,
// block-partitioned) -> k_router (128x64, float4 swg, LDS histogram) ->
// k_scatter (LDS-aggregated cursor claim) -> k_expert (bf16 MFMA 128x128,
// BK=64, dbuf, global_load_lds w/ pre-swizzled src, XCD chunking, bf16
// contrib) -> k_reduce (y = contrib[p0] + contrib[p1]).

#define N_TOK 8192
#define DIM   1024
#define DHID  256
#define DOUT  1024
#define NE    20
#define BM2   128
#define BN2   128
#define BK2   64
// sum_e ceil(cnt_e/128) <= 16384/128 + 20 = 148
#define MAX_TT 148

typedef __attribute__((ext_vector_type(8))) short bf16x8;
typedef __attribute__((ext_vector_type(4))) float f32x4;

__device__ __forceinline__ float gelu_erf(float v) {
    return 0.5f * v * (1.0f + erff(v * 0.70710678118654752f));
}

__device__ __forceinline__ ushort f2b(float f) {
  union { float f; uint u; } c; c.f = f;
  uint r = (c.u + 0x7FFFu + ((c.u >> 16) & 1u)) >> 16;  // RNE
  return (ushort)r;
}

__device__ __forceinline__ float b2f(ushort u) {
  union { uint u; float f; } c; c.u = ((uint)u) << 16;
  return c.f;
}

// ============ k_front: [0,512) gate GEMM | [512,5632) We->bf16T | [5632,7680) x->bf16
__global__ __launch_bounds__(256) void k_front(
    const float* __restrict__ x, const float* __restrict__ wg1,
    const float* __restrict__ bg1, float* __restrict__ h,
    const float* __restrict__ We, ushort* __restrict__ weT,
    ushort* __restrict__ xb) {
  __shared__ __align__(1024) char smem[32768];
  const int bid = blockIdx.x;
  const int t = threadIdx.x;

  if (bid < 512) {
    // ---- gating GEMM: h = gelu(x @ wg1 + bg1), 64x64 tile, fp32, dbuf ----
    // buf layout: buf0 Xs@0 Ws@8192 | buf1 Xs@16384 Ws@24576
    // Xs [64 rows][32 k], slot phys = seg ^ ((row>>2)&7) (conflict-free);
    // staged by global_load_lds: linear dest + pre-XOR'd source (rule #21).
    const int ty = t >> 4, tx = t & 15;
    const int m0 = (bid >> 2) * 64;
    const int c0 = (bid & 3) * 64;

    const float* xsrc[2];
    const float* wsrc[2];
    int dsto[4];                       // byte offsets in smem for dests
#pragma unroll
    for (int l = 0; l < 2; ++l) {
      int i = t + l * 256;
      int row = i >> 3, seg = i & 7;
      xsrc[l] = x + (size_t)(m0 + row) * DIM + ((seg ^ ((row >> 2) & 7)) << 2);
      dsto[l] = i * 16;                // Xs dest
      int kk = i >> 4, sg2 = i & 15;
      wsrc[l] = wg1 + (size_t)kk * DHID + c0 + sg2 * 4;
      dsto[2 + l] = 8192 + i * 16;     // Ws dest
    }

    // prologue: stage k0=0 into buf0
#pragma unroll
    for (int l = 0; l < 2; ++l)
      __builtin_amdgcn_global_load_lds(xsrc[l], (float*)(smem + dsto[l]), 16, 0, 0);
#pragma unroll
    for (int l = 0; l < 2; ++l)
      __builtin_amdgcn_global_load_lds(wsrc[l], (float*)(smem + dsto[2 + l]), 16, 0, 0);

    float acc[4][4] = {};
    int cur = 0;
    for (int k0 = 0; k0 < DIM; k0 += 32) {
      __syncthreads();   // buf[cur] staged; prev readers of buf[nxt] done
      if (k0 + 32 < DIM) {
        const int koff = k0 + 32;
        const int dsh = (cur ^ 1) ? 16384 : 0;
#pragma unroll
        for (int l = 0; l < 2; ++l)
          __builtin_amdgcn_global_load_lds(xsrc[l] + koff,
                                           (float*)(smem + dsh + dsto[l]), 16, 0, 0);
#pragma unroll
        for (int l = 0; l < 2; ++l)
          __builtin_amdgcn_global_load_lds(wsrc[l] + (size_t)koff * DHID,
                                           (float*)(smem + dsh + dsto[2 + l]), 16, 0, 0);
      }
      const char* XsB = smem + (cur ? 16384 : 0);
      const float (*Ws)[64] = (const float(*)[64])(XsB + 8192);
#pragma unroll
      for (int q = 0; q < 8; ++q) {          // k-quads, ascending
        float4 a[4];
        const int qs = (q ^ (ty & 7)) << 4;
#pragma unroll
        for (int i = 0; i < 4; ++i)
          a[i] = *(const float4*)(XsB + (ty * 4 + i) * 128 + qs);
#pragma unroll
        for (int u = 0; u < 4; ++u) {        // k within quad, ascending
          float4 b = *(const float4*)&Ws[q * 4 + u][tx * 4];
#pragma unroll
          for (int i = 0; i < 4; ++i) {
            float av = reinterpret_cast<const float*>(&a[i])[u];
            acc[i][0] += av * b.x;
            acc[i][1] += av * b.y;
            acc[i][2] += av * b.z;
            acc[i][3] += av * b.w;
          }
        }
      }
      cur ^= 1;
    }
#pragma unroll
    for (int i = 0; i < 4; ++i) {
      int row = m0 + ty * 4 + i;
      int col = c0 + tx * 4;
      float4 o;
      o.x = gelu_erf(acc[i][0] + bg1[col + 0]);
      o.y = gelu_erf(acc[i][1] + bg1[col + 1]);
      o.z = gelu_erf(acc[i][2] + bg1[col + 2]);
      o.w = gelu_erf(acc[i][3] + bg1[col + 3]);
      *(float4*)&h[(size_t)row * DHID + col] = o;
    }
  } else if (bid < 5632) {
    // ---- We [e][k][n] fp32 -> weT [e][n][k] bf16 (conflict-free) ----
    ushort* Ts = (ushort*)smem;                            // 8192 B
    const int b = bid - 512;
    const int e = b >> 8, rem = b & 255;
    const int k0 = (rem >> 4) * 64;
    const int n0 = (rem & 15) * 64;
    const float* src = We + ((size_t)e << 20);
    const int m = t & 15;
    const int xk = (m & 7) << 3;
#pragma unroll
    for (int it = 0; it < 4; ++it) {
      int kk = it * 16 + (t >> 4);
      int nn = m * 4;
      float4 v = *(const float4*)(src + (size_t)(k0 + kk) * DOUT + n0 + nn);
      int col = kk ^ xk;
      Ts[(nn + 0) * 64 + col] = f2b(v.x);
      Ts[(nn + 1) * 64 + col] = f2b(v.y);
      Ts[(nn + 2) * 64 + col] = f2b(v.z);
      Ts[(nn + 3) * 64 + col] = f2b(v.w);
    }
    __syncthreads();
    ushort* dst = weT + ((size_t)e << 20);
#pragma unroll
    for (int it = 0; it < 2; ++it) {
      int nn = it * 32 + (t >> 3);
      int ks = (t & 7) * 8;
      int cs = ks ^ (((nn >> 2) & 7) << 3);
      uint4 v = *(const uint4*)&Ts[nn * 64 + cs];
      *(uint4*)(dst + (size_t)(n0 + nn) * DIM + k0 + ks) = v;
    }
  } else {
    // ---- x fp32 -> bf16, 16 elems/thread ----
    const size_t i0 = (((size_t)(bid - 5632)) * 256 + t) * 16;
    ushort o[16];
#pragma unroll
    for (int j = 0; j < 4; ++j) {
      float4 v = *(const float4*)(x + i0 + j * 4);
      o[j * 4 + 0] = f2b(v.x); o[j * 4 + 1] = f2b(v.y);
      o[j * 4 + 2] = f2b(v.z); o[j * 4 + 3] = f2b(v.w);
    }
    *(uint4*)(xb + i0)     = *(const uint4*)&o[0];
    *(uint4*)(xb + i0 + 8) = *(const uint4*)&o[8];
  }
}

// -------- router: logits = (h@wg2+bg2)[:, :20], softmax, top-2, counts -------
// 128 blocks x 64 threads; float4 swg reads; per-block LDS histogram.
__global__ __launch_bounds__(64) void k_router(
    const float* __restrict__ h, const float* __restrict__ wg2,
    const float* __restrict__ bg2, int* __restrict__ tokexp,
    float* __restrict__ tokgate, int* __restrict__ counts) {
  __shared__ float swg[DHID * NE];   // 20 KB
  __shared__ int hist[NE];
  const int t = threadIdx.x;
  if (t < NE) hist[t] = 0;
  for (int i = t; i < DHID * NE; i += 64) {
    int k = i / NE, j = i - k * NE;
    swg[i] = wg2[(size_t)k * (2 * NE) + j];
  }
  __syncthreads();
  const int n = blockIdx.x * 64 + t;
  float s[NE];
#pragma unroll
  for (int j = 0; j < NE; ++j) s[j] = bg2[j];
  const float* hr = h + (size_t)n * DHID;
  for (int k = 0; k < DHID; k += 4) {
    float4 hv = *(const float4*)(hr + k);
#pragma unroll
    for (int u = 0; u < 4; ++u) {
      float hvu = reinterpret_cast<const float*>(&hv)[u];
      const float4* wrow = (const float4*)&swg[(k + u) * NE];
      float wl[NE];
      *(float4*)&wl[0]  = wrow[0];
      *(float4*)&wl[4]  = wrow[1];
      *(float4*)&wl[8]  = wrow[2];
      *(float4*)&wl[12] = wrow[3];
      *(float4*)&wl[16] = wrow[4];
#pragma unroll
      for (int j = 0; j < NE; ++j) s[j] += hvu * wl[j];
    }
  }
  float m = s[0];
#pragma unroll
  for (int j = 1; j < NE; ++j) m = fmaxf(m, s[j]);
  float sum = 0.0f;
#pragma unroll
  for (int j = 0; j < NE; ++j) { s[j] = expf(s[j] - m); sum += s[j]; }
  float inv = 1.0f / sum;
#pragma unroll
  for (int j = 0; j < NE; ++j) s[j] *= inv;
  int j0 = 0; float v0 = s[0];
#pragma unroll
  for (int j = 1; j < NE; ++j) if (s[j] > v0) { v0 = s[j]; j0 = j; }
  int j1 = -1; float v1 = -1.0f;
#pragma unroll
  for (int j = 0; j < NE; ++j)
    if (j != j0 && s[j] > v1) { v1 = s[j]; j1 = j; }
  tokexp[2 * n + 0] = j0;  tokgate[2 * n + 0] = v0;
  tokexp[2 * n + 1] = j1;  tokgate[2 * n + 1] = v1;
  atomicAdd(&hist[j0], 1);
  atomicAdd(&hist[j1], 1);
  __syncthreads();
  if (t < NE) atomicAdd(&counts[t], hist[t]);
}

// ------ scatter: LDS-aggregated cursor claim ---------------------------------
__global__ __launch_bounds__(256) void k_scatter(
    const int* __restrict__ tokexp, const float* __restrict__ tokgate,
    const int* __restrict__ counts, int* __restrict__ zcur,
    int* __restrict__ perm, float* __restrict__ pgate, int* __restrict__ inv) {
  __shared__ int soff[NE], lcnt[NE], lbase[NE];
  const int t = threadIdx.x;
  if (t < NE) lcnt[t] = 0;
  if (t < 64) {
    int c = (t < NE) ? counts[t] : 0;
    int cs = c;
    for (int d = 1; d < 64; d <<= 1) {
      int u = __shfl_up(cs, d); if (t >= d) cs += u;
    }
    if (t < NE) soff[t] = cs - c;
  }
  __syncthreads();
  const int n = blockIdx.x * 256 + t;
  const int e0 = tokexp[2 * n + 0];
  const int e1 = tokexp[2 * n + 1];
  const int r0 = atomicAdd(&lcnt[e0], 1);
  const int r1 = atomicAdd(&lcnt[e1], 1);
  __syncthreads();
  if (t < NE) lbase[t] = atomicAdd(&zcur[t], lcnt[t]);
  __syncthreads();
  {
    int pos = soff[e0] + lbase[e0] + r0;
    perm[pos] = n;
    pgate[pos] = tokgate[2 * n + 0];
    inv[2 * n + 0] = pos;
  }
  {
    int pos = soff[e1] + lbase[e1] + r1;
    perm[pos] = n;
    pgate[pos] = tokgate[2 * n + 1];
    inv[2 * n + 1] = pos;
  }
}

// ------ grouped expert GEMM (bf16 MFMA): contrib[pos] = g*(x@We[e]+be[e]) ----
// 128x128 tile, BK=64, 2-phase double-buffered LDS. In-block prefix.
__global__ __launch_bounds__(256) void k_expert(
    const ushort* __restrict__ xb, const ushort* __restrict__ weT,
    const float* __restrict__ be, const int* __restrict__ perm,
    const float* __restrict__ pgate, const int* __restrict__ counts,
    ushort* __restrict__ contrib) {
  // XCD-chunked swizzle: 1184 blocks = 8 XCDs x 148
  const int lin = blockIdx.x + blockIdx.y * MAX_TT;
  const int nt8 = (lin & 7) * MAX_TT + (lin >> 3);
  const int rt = nt8 >> 3, pn = nt8 & 7;

  __shared__ __align__(1024) char smem[66560];
  int*    stok  = (int*)smem;
  float*  sgate = (float*)(smem + 512);
  ushort* As0   = (ushort*)(smem + 1024);
  ushort* Bs0   = (ushort*)(smem + 17408);
  __shared__ int tinfo[3];

  const int t = threadIdx.x;
  if (t < 64) {
    if (t == 0) tinfo[0] = -1;
    int c = (t < NE) ? counts[t] : 0;
    int nt = (c + BM2 - 1) >> 7;
    int cs = c, ts = nt;
    for (int d = 1; d < 64; d <<= 1) {
      int u = __shfl_up(cs, d); if (t >= d) cs += u;
      int v = __shfl_up(ts, d); if (t >= d) ts += v;
    }
    int coff = cs - c, toff = ts - nt;
    if (t < NE && rt >= toff && rt < toff + nt) {
      int i = rt - toff;
      tinfo[0] = t;
      tinfo[1] = coff + i * BM2;
      tinfo[2] = min(BM2, c - i * BM2);
    }
  }
  __syncthreads();
  if (tinfo[0] < 0) return;
  const int e = tinfo[0], rs = tinfo[1], cnt = tinfo[2];
  const int c0 = pn * BN2;

  if (t < BM2) {
    int r = (t < cnt) ? rs + t : rs;
    stok[t]  = perm[r];
    sgate[t] = (t < cnt) ? pgate[rs + t] : 0.0f;
  }
  __syncthreads();
  const int lane = t & 63, w = t >> 6;
  const int wr = w >> 1, wc = w & 1;
  const int lr = lane & 15, hi = lane >> 4;
  const int srow = lane >> 3, sseg = lane & 7;

  const ushort* asrc[4];
  const ushort* bsrc[4];
  ushort* adst[4];
  ushort* bdst[4];
#pragma unroll
  for (int l = 0; l < 4; ++l) {
    int r = w * 32 + l * 8 + srow;                    // 0..127
    asrc[l] = xb + (size_t)stok[r] * DIM + ((sseg ^ (r & 7)) << 3);
    adst[l] = As0 + (w * 32 + l * 8) * BK2;
    bsrc[l] = weT + ((size_t)e << 20) + (size_t)(c0 + r) * DIM + ((sseg ^ (r & 7)) << 3);
    bdst[l] = Bs0 + (w * 32 + l * 8) * BK2;
  }

  f32x4 acc[4][4] = {};

  // prologue: stage k=0 into buf0
#pragma unroll
  for (int l = 0; l < 4; ++l)
    __builtin_amdgcn_global_load_lds(asrc[l], adst[l], 16, 0, 0);
#pragma unroll
  for (int l = 0; l < 4; ++l)
    __builtin_amdgcn_global_load_lds(bsrc[l], bdst[l], 16, 0, 0);

  int cur = 0;
  for (int k0 = 0; k0 < DIM; k0 += BK2) {
    __syncthreads();   // buf[cur] ready; prev readers of buf[nxt] done
    const int nxt = cur ^ 1;
    if (k0 + BK2 < DIM) {
      const int koff = k0 + BK2;
      const int dsh = nxt ? 16384 : 0;
#pragma unroll
      for (int l = 0; l < 4; ++l)
        __builtin_amdgcn_global_load_lds(asrc[l] + koff, adst[l] + dsh, 16, 0, 0);
#pragma unroll
      for (int l = 0; l < 4; ++l)
        __builtin_amdgcn_global_load_lds(bsrc[l] + koff, bdst[l] + dsh, 16, 0, 0);
    }
    const char* Ab = (const char*)smem + 1024 + (cur ? 32768 : 0);
    const char* Bb = Ab + 16384;
#pragma unroll
    for (int ks = 0; ks < 2; ++ks) {
      const int kb = ks * 64 + hi * 16;
      bf16x8 af[4], bfr[4];
#pragma unroll
      for (int mi = 0; mi < 4; ++mi) {
        int r = wr * 64 + mi * 16 + lr;
        af[mi] = *(const bf16x8*)(Ab + r * 128 + (kb ^ ((r & 7) << 4)));
      }
#pragma unroll
      for (int ni = 0; ni < 4; ++ni) {
        int n = wc * 64 + ni * 16 + lr;
        bfr[ni] = *(const bf16x8*)(Bb + n * 128 + (kb ^ ((n & 7) << 4)));
      }
#pragma unroll
      for (int mi = 0; mi < 4; ++mi)
#pragma unroll
        for (int ni = 0; ni < 4; ++ni)
          acc[mi][ni] = __builtin_amdgcn_mfma_f32_16x16x32_bf16(
              af[mi], bfr[ni], acc[mi][ni], 0, 0, 0);
    }
    cur = nxt;
  }
  __syncthreads();

  // ---- epilogue: gate+bias in fp32, bf16 LDS transpose, uint4 stores ----
  ushort (*Ep)[72] = (ushort(*)[72])(smem + 1024 + w * 9216);  // [64][72]
  float bcol[4];
#pragma unroll
  for (int ni = 0; ni < 4; ++ni)
    bcol[ni] = be[(size_t)e * DOUT + c0 + wc * 64 + ni * 16 + lr];
#pragma unroll
  for (int mi = 0; mi < 4; ++mi)
#pragma unroll
    for (int r = 0; r < 4; ++r) {
      int rowl = mi * 16 + hi * 4 + r;      // C/D: col=lane&15, row=(lane>>4)*4+reg
      float g = sgate[wr * 64 + rowl];
#pragma unroll
      for (int ni = 0; ni < 4; ++ni)
        Ep[rowl][ni * 16 + lr] = f2b(g * (acc[mi][ni][r] + bcol[ni]));
    }
  __syncthreads();
#pragma unroll
  for (int it = 0; it < 8; ++it) {
    int rowl = it * 8 + (lane >> 3);
    int slotL = wr * 64 + rowl;
    if (slotL < cnt) {
      uint4 v = *(const uint4*)&Ep[rowl][(lane & 7) * 8];
      *(uint4*)(contrib + (size_t)(rs + slotL) * DOUT + c0 + wc * 64 + (lane & 7) * 8) = v;
    }
  }
}

// --------- reduce: y[n] = contrib[inv[2n]] + contrib[inv[2n+1]] --------------
__global__ __launch_bounds__(256) void k_reduce(
    const ushort* __restrict__ contrib, const int* __restrict__ inv,
    float* __restrict__ y) {
  const int t = threadIdx.x;
  const int n = blockIdx.x * 2 + (t >> 7);
  const int c = (t & 127) * 8;
  const int p0 = inv[2 * n], p1 = inv[2 * n + 1];
  uint4 a = *(const uint4*)(contrib + (size_t)p0 * DOUT + c);
  uint4 b = *(const uint4*)(contrib + (size_t)p1 * DOUT + c);
  const ushort* ua = (const ushort*)&a;
  const ushort* ub = (const ushort*)&b;
  float4 o0, o1;
  o0.x = b2f(ua[0]) + b2f(ub[0]);
  o0.y = b2f(ua[1]) + b2f(ub[1]);
  o0.z = b2f(ua[2]) + b2f(ub[2]);
  o0.w = b2f(ua[3]) + b2f(ub[3]);
  o1.x = b2f(ua[4]) + b2f(ub[4]);
  o1.y = b2f(ua[5]) + b2f(ub[5]);
  o1.z = b2f(ua[6]) + b2f(ub[6]);
  o1.w = b2f(ua[7]) + b2f(ub[7]);
  float* yr = y + (size_t)n * DOUT + c;
  *(float4*)yr = o0;
  *(float4*)(yr + 4) = o1;
}

extern "C" void kernel_launch(void* const* d_in, const int* in_sizes, int n_in,
                              void* d_out, int out_size, void* d_ws, size_t ws_size,
                              hipStream_t stream) {
  (void)in_sizes; (void)n_in; (void)ws_size; (void)out_size;
  const float* x   = (const float*)d_in[0];
  const float* wg1 = (const float*)d_in[1];
  const float* bg1 = (const float*)d_in[2];
  const float* wg2 = (const float*)d_in[3];
  const float* bg2 = (const float*)d_in[4];
  const float* We  = (const float*)d_in[5];
  const float* be  = (const float*)d_in[6];
  float* y = (float*)d_out;

  char* ws = (char*)d_ws;
  float*  h       = (float*)ws;                                      // 8 MB
  ushort* xb      = (ushort*)(ws + (size_t)N_TOK * DHID * 4);        // 16 MB
  ushort* weT     = (ushort*)((char*)xb + (size_t)N_TOK * DIM * 2);  // 40 MB
  ushort* contrib = (ushort*)((char*)weT + (size_t)NE * DIM * DOUT * 2);  // 32 MB
  char*   ctrl    = (char*)contrib + (size_t)2 * N_TOK * DOUT * 2;
  int*   counts  = (int*)ctrl;
  int*   zcur    = counts + 64;                      // zeroed by memset below
  int*   tokexp  = counts + 128;
  float* tokgate = (float*)(tokexp + 2 * N_TOK);
  int*   perm    = (int*)(tokgate + 2 * N_TOK);
  float* pgate   = (float*)(perm + 2 * N_TOK);
  int*   inv     = (int*)(pgate + 2 * N_TOK);

  hipMemsetAsync(counts, 0, 128 * sizeof(int), stream);

  k_front<<<dim3(512 + 5120 + 2048), 256, 0, stream>>>(x, wg1, bg1, h, We, weT, xb);
  k_router<<<dim3(N_TOK / 64), 64, 0, stream>>>(h, wg2, bg2, tokexp, tokgate, counts);
  k_scatter<<<dim3(N_TOK / 256), 256, 0, stream>>>(tokexp, tokgate, counts, zcur,
                                                   perm, pgate, inv);
  k_expert<<<dim3(MAX_TT, DOUT / BN2), 256, 0, stream>>>(
      xb, weT, be, perm, pgate, counts, contrib);
  k_reduce<<<dim3(N_TOK / 2), 256, 0, stream>>>(contrib, inv, y);
}

// Round 21
// 180.247 us; speedup vs baseline: 1.1213x; 1.0246x over previous
//
#include <hip/hip_runtime.h>
#include <hip/hip_bf16.h>
#include <math.h>

// MoE: B=4,S=2048 -> N=8192 tokens, D=1024, DO=1024, E=20 experts, top-2.
// R21: R20 (best, 184.7us) + counts/zcur zeroing folded into k_front's last
// block (stream order: all k_front completes before k_router) -> removes the
// hipMemsetAsync dispatch. Everything else byte-identical to R20.

#define N_TOK 8192
#define DIM   1024
#define DHID  256
#define DOUT  1024
#define NE    20
#define BM2   128
#define BN2   128
#define BK2   64
// sum_e ceil(cnt_e/128) <= 16384/128 + 20 = 148
#define MAX_TT 148

typedef __attribute__((ext_vector_type(8))) short bf16x8;
typedef __attribute__((ext_vector_type(4))) float f32x4;

__device__ __forceinline__ float gelu_erf(float v) {
    return 0.5f * v * (1.0f + erff(v * 0.70710678118654752f));
}

__device__ __forceinline__ ushort f2b(float f) {
  union { float f; uint u; } c; c.f = f;
  uint r = (c.u + 0x7FFFu + ((c.u >> 16) & 1u)) >> 16;  // RNE
  return (ushort)r;
}

__device__ __forceinline__ float b2f(ushort u) {
  union { uint u; float f; } c; c.u = ((uint)u) << 16;
  return c.f;
}

// ============ k_front: [0,512) gate GEMM | [512,5632) We->bf16T | [5632,7680) x->bf16
__global__ __launch_bounds__(256) void k_front(
    const float* __restrict__ x, const float* __restrict__ wg1,
    const float* __restrict__ bg1, float* __restrict__ h,
    const float* __restrict__ We, ushort* __restrict__ weT,
    ushort* __restrict__ xb, int* __restrict__ counts) {
  __shared__ __align__(1024) char smem[32768];
  const int bid = blockIdx.x;
  const int t = threadIdx.x;

  if (bid < 512) {
    // ---- gating GEMM: h = gelu(x @ wg1 + bg1), 64x64 tile, fp32, dbuf ----
    // buf layout: buf0 Xs@0 Ws@8192 | buf1 Xs@16384 Ws@24576
    // Xs [64 rows][32 k], slot phys = seg ^ ((row>>2)&7) (conflict-free);
    // staged by global_load_lds: linear dest + pre-XOR'd source (rule #21).
    const int ty = t >> 4, tx = t & 15;
    const int m0 = (bid >> 2) * 64;
    const int c0 = (bid & 3) * 64;

    const float* xsrc[2];
    const float* wsrc[2];
    int dsto[4];                       // byte offsets in smem for dests
#pragma unroll
    for (int l = 0; l < 2; ++l) {
      int i = t + l * 256;
      int row = i >> 3, seg = i & 7;
      xsrc[l] = x + (size_t)(m0 + row) * DIM + ((seg ^ ((row >> 2) & 7)) << 2);
      dsto[l] = i * 16;                // Xs dest
      int kk = i >> 4, sg2 = i & 15;
      wsrc[l] = wg1 + (size_t)kk * DHID + c0 + sg2 * 4;
      dsto[2 + l] = 8192 + i * 16;     // Ws dest
    }

    // prologue: stage k0=0 into buf0
#pragma unroll
    for (int l = 0; l < 2; ++l)
      __builtin_amdgcn_global_load_lds(xsrc[l], (float*)(smem + dsto[l]), 16, 0, 0);
#pragma unroll
    for (int l = 0; l < 2; ++l)
      __builtin_amdgcn_global_load_lds(wsrc[l], (float*)(smem + dsto[2 + l]), 16, 0, 0);

    float acc[4][4] = {};
    int cur = 0;
    for (int k0 = 0; k0 < DIM; k0 += 32) {
      __syncthreads();   // buf[cur] staged; prev readers of buf[nxt] done
      if (k0 + 32 < DIM) {
        const int koff = k0 + 32;
        const int dsh = (cur ^ 1) ? 16384 : 0;
#pragma unroll
        for (int l = 0; l < 2; ++l)
          __builtin_amdgcn_global_load_lds(xsrc[l] + koff,
                                           (float*)(smem + dsh + dsto[l]), 16, 0, 0);
#pragma unroll
        for (int l = 0; l < 2; ++l)
          __builtin_amdgcn_global_load_lds(wsrc[l] + (size_t)koff * DHID,
                                           (float*)(smem + dsh + dsto[2 + l]), 16, 0, 0);
      }
      const char* XsB = smem + (cur ? 16384 : 0);
      const float (*Ws)[64] = (const float(*)[64])(XsB + 8192);
#pragma unroll
      for (int q = 0; q < 8; ++q) {          // k-quads, ascending
        float4 a[4];
        const int qs = (q ^ (ty & 7)) << 4;
#pragma unroll
        for (int i = 0; i < 4; ++i)
          a[i] = *(const float4*)(XsB + (ty * 4 + i) * 128 + qs);
#pragma unroll
        for (int u = 0; u < 4; ++u) {        // k within quad, ascending
          float4 b = *(const float4*)&Ws[q * 4 + u][tx * 4];
#pragma unroll
          for (int i = 0; i < 4; ++i) {
            float av = reinterpret_cast<const float*>(&a[i])[u];
            acc[i][0] += av * b.x;
            acc[i][1] += av * b.y;
            acc[i][2] += av * b.z;
            acc[i][3] += av * b.w;
          }
        }
      }
      cur ^= 1;
    }
#pragma unroll
    for (int i = 0; i < 4; ++i) {
      int row = m0 + ty * 4 + i;
      int col = c0 + tx * 4;
      float4 o;
      o.x = gelu_erf(acc[i][0] + bg1[col + 0]);
      o.y = gelu_erf(acc[i][1] + bg1[col + 1]);
      o.z = gelu_erf(acc[i][2] + bg1[col + 2]);
      o.w = gelu_erf(acc[i][3] + bg1[col + 3]);
      *(float4*)&h[(size_t)row * DHID + col] = o;
    }
  } else if (bid < 5632) {
    // ---- We [e][k][n] fp32 -> weT [e][n][k] bf16 (conflict-free) ----
    ushort* Ts = (ushort*)smem;                            // 8192 B
    const int b = bid - 512;
    const int e = b >> 8, rem = b & 255;
    const int k0 = (rem >> 4) * 64;
    const int n0 = (rem & 15) * 64;
    const float* src = We + ((size_t)e << 20);
    const int m = t & 15;
    const int xk = (m & 7) << 3;
#pragma unroll
    for (int it = 0; it < 4; ++it) {
      int kk = it * 16 + (t >> 4);
      int nn = m * 4;
      float4 v = *(const float4*)(src + (size_t)(k0 + kk) * DOUT + n0 + nn);
      int col = kk ^ xk;
      Ts[(nn + 0) * 64 + col] = f2b(v.x);
      Ts[(nn + 1) * 64 + col] = f2b(v.y);
      Ts[(nn + 2) * 64 + col] = f2b(v.z);
      Ts[(nn + 3) * 64 + col] = f2b(v.w);
    }
    __syncthreads();
    ushort* dst = weT + ((size_t)e << 20);
#pragma unroll
    for (int it = 0; it < 2; ++it) {
      int nn = it * 32 + (t >> 3);
      int ks = (t & 7) * 8;
      int cs = ks ^ (((nn >> 2) & 7) << 3);
      uint4 v = *(const uint4*)&Ts[nn * 64 + cs];
      *(uint4*)(dst + (size_t)(n0 + nn) * DIM + k0 + ks) = v;
    }
  } else {
    // ---- x fp32 -> bf16, 16 elems/thread; last block zeroes counts/zcur ----
    if (bid == 7679 && t < 128) counts[t] = 0;   // replaces hipMemsetAsync
    const size_t i0 = (((size_t)(bid - 5632)) * 256 + t) * 16;
    ushort o[16];
#pragma unroll
    for (int j = 0; j < 4; ++j) {
      float4 v = *(const float4*)(x + i0 + j * 4);
      o[j * 4 + 0] = f2b(v.x); o[j * 4 + 1] = f2b(v.y);
      o[j * 4 + 2] = f2b(v.z); o[j * 4 + 3] = f2b(v.w);
    }
    *(uint4*)(xb + i0)     = *(const uint4*)&o[0];
    *(uint4*)(xb + i0 + 8) = *(const uint4*)&o[8];
  }
}

// -------- router: logits = (h@wg2+bg2)[:, :20], softmax, top-2, counts -------
// 128 blocks x 64 threads; float4 swg reads; per-block LDS histogram.
__global__ __launch_bounds__(64) void k_router(
    const float* __restrict__ h, const float* __restrict__ wg2,
    const float* __restrict__ bg2, int* __restrict__ tokexp,
    float* __restrict__ tokgate, int* __restrict__ counts) {
  __shared__ float swg[DHID * NE];   // 20 KB
  __shared__ int hist[NE];
  const int t = threadIdx.x;
  if (t < NE) hist[t] = 0;
  for (int i = t; i < DHID * NE; i += 64) {
    int k = i / NE, j = i - k * NE;
    swg[i] = wg2[(size_t)k * (2 * NE) + j];
  }
  __syncthreads();
  const int n = blockIdx.x * 64 + t;
  float s[NE];
#pragma unroll
  for (int j = 0; j < NE; ++j) s[j] = bg2[j];
  const float* hr = h + (size_t)n * DHID;
  for (int k = 0; k < DHID; k += 4) {
    float4 hv = *(const float4*)(hr + k);
#pragma unroll
    for (int u = 0; u < 4; ++u) {
      float hvu = reinterpret_cast<const float*>(&hv)[u];
      const float4* wrow = (const float4*)&swg[(k + u) * NE];
      float wl[NE];
      *(float4*)&wl[0]  = wrow[0];
      *(float4*)&wl[4]  = wrow[1];
      *(float4*)&wl[8]  = wrow[2];
      *(float4*)&wl[12] = wrow[3];
      *(float4*)&wl[16] = wrow[4];
#pragma unroll
      for (int j = 0; j < NE; ++j) s[j] += hvu * wl[j];
    }
  }
  float m = s[0];
#pragma unroll
  for (int j = 1; j < NE; ++j) m = fmaxf(m, s[j]);
  float sum = 0.0f;
#pragma unroll
  for (int j = 0; j < NE; ++j) { s[j] = expf(s[j] - m); sum += s[j]; }
  float inv = 1.0f / sum;
#pragma unroll
  for (int j = 0; j < NE; ++j) s[j] *= inv;
  int j0 = 0; float v0 = s[0];
#pragma unroll
  for (int j = 1; j < NE; ++j) if (s[j] > v0) { v0 = s[j]; j0 = j; }
  int j1 = -1; float v1 = -1.0f;
#pragma unroll
  for (int j = 0; j < NE; ++j)
    if (j != j0 && s[j] > v1) { v1 = s[j]; j1 = j; }
  tokexp[2 * n + 0] = j0;  tokgate[2 * n + 0] = v0;
  tokexp[2 * n + 1] = j1;  tokgate[2 * n + 1] = v1;
  atomicAdd(&hist[j0], 1);
  atomicAdd(&hist[j1], 1);
  __syncthreads();
  if (t < NE) atomicAdd(&counts[t], hist[t]);
}

// ------ scatter: LDS-aggregated cursor claim ---------------------------------
__global__ __launch_bounds__(256) void k_scatter(
    const int* __restrict__ tokexp, const float* __restrict__ tokgate,
    const int* __restrict__ counts, int* __restrict__ zcur,
    int* __restrict__ perm, float* __restrict__ pgate, int* __restrict__ inv) {
  __shared__ int soff[NE], lcnt[NE], lbase[NE];
  const int t = threadIdx.x;
  if (t < NE) lcnt[t] = 0;
  if (t < 64) {
    int c = (t < NE) ? counts[t] : 0;
    int cs = c;
    for (int d = 1; d < 64; d <<= 1) {
      int u = __shfl_up(cs, d); if (t >= d) cs += u;
    }
    if (t < NE) soff[t] = cs - c;
  }
  __syncthreads();
  const int n = blockIdx.x * 256 + t;
  const int e0 = tokexp[2 * n + 0];
  const int e1 = tokexp[2 * n + 1];
  const int r0 = atomicAdd(&lcnt[e0], 1);
  const int r1 = atomicAdd(&lcnt[e1], 1);
  __syncthreads();
  if (t < NE) lbase[t] = atomicAdd(&zcur[t], lcnt[t]);
  __syncthreads();
  {
    int pos = soff[e0] + lbase[e0] + r0;
    perm[pos] = n;
    pgate[pos] = tokgate[2 * n + 0];
    inv[2 * n + 0] = pos;
  }
  {
    int pos = soff[e1] + lbase[e1] + r1;
    perm[pos] = n;
    pgate[pos] = tokgate[2 * n + 1];
    inv[2 * n + 1] = pos;
  }
}

// ------ grouped expert GEMM (bf16 MFMA): contrib[pos] = g*(x@We[e]+be[e]) ----
// 128x128 tile, BK=64, 2-phase double-buffered LDS. In-block prefix.
__global__ __launch_bounds__(256) void k_expert(
    const ushort* __restrict__ xb, const ushort* __restrict__ weT,
    const float* __restrict__ be, const int* __restrict__ perm,
    const float* __restrict__ pgate, const int* __restrict__ counts,
    ushort* __restrict__ contrib) {
  // XCD-chunked swizzle: 1184 blocks = 8 XCDs x 148
  const int lin = blockIdx.x + blockIdx.y * MAX_TT;
  const int nt8 = (lin & 7) * MAX_TT + (lin >> 3);
  const int rt = nt8 >> 3, pn = nt8 & 7;

  __shared__ __align__(1024) char smem[66560];
  int*    stok  = (int*)smem;
  float*  sgate = (float*)(smem + 512);
  ushort* As0   = (ushort*)(smem + 1024);
  ushort* Bs0   = (ushort*)(smem + 17408);
  __shared__ int tinfo[3];

  const int t = threadIdx.x;
  if (t < 64) {
    if (t == 0) tinfo[0] = -1;
    int c = (t < NE) ? counts[t] : 0;
    int nt = (c + BM2 - 1) >> 7;
    int cs = c, ts = nt;
    for (int d = 1; d < 64; d <<= 1) {
      int u = __shfl_up(cs, d); if (t >= d) cs += u;
      int v = __shfl_up(ts, d); if (t >= d) ts += v;
    }
    int coff = cs - c, toff = ts - nt;
    if (t < NE && rt >= toff && rt < toff + nt) {
      int i = rt - toff;
      tinfo[0] = t;
      tinfo[1] = coff + i * BM2;
      tinfo[2] = min(BM2, c - i * BM2);
    }
  }
  __syncthreads();
  if (tinfo[0] < 0) return;
  const int e = tinfo[0], rs = tinfo[1], cnt = tinfo[2];
  const int c0 = pn * BN2;

  if (t < BM2) {
    int r = (t < cnt) ? rs + t : rs;
    stok[t]  = perm[r];
    sgate[t] = (t < cnt) ? pgate[rs + t] : 0.0f;
  }
  __syncthreads();
  const int lane = t & 63, w = t >> 6;
  const int wr = w >> 1, wc = w & 1;
  const int lr = lane & 15, hi = lane >> 4;
  const int srow = lane >> 3, sseg = lane & 7;

  const ushort* asrc[4];
  const ushort* bsrc[4];
  ushort* adst[4];
  ushort* bdst[4];
#pragma unroll
  for (int l = 0; l < 4; ++l) {
    int r = w * 32 + l * 8 + srow;                    // 0..127
    asrc[l] = xb + (size_t)stok[r] * DIM + ((sseg ^ (r & 7)) << 3);
    adst[l] = As0 + (w * 32 + l * 8) * BK2;
    bsrc[l] = weT + ((size_t)e << 20) + (size_t)(c0 + r) * DIM + ((sseg ^ (r & 7)) << 3);
    bdst[l] = Bs0 + (w * 32 + l * 8) * BK2;
  }

  f32x4 acc[4][4] = {};

  // prologue: stage k=0 into buf0
#pragma unroll
  for (int l = 0; l < 4; ++l)
    __builtin_amdgcn_global_load_lds(asrc[l], adst[l], 16, 0, 0);
#pragma unroll
  for (int l = 0; l < 4; ++l)
    __builtin_amdgcn_global_load_lds(bsrc[l], bdst[l], 16, 0, 0);

  int cur = 0;
  for (int k0 = 0; k0 < DIM; k0 += BK2) {
    __syncthreads();   // buf[cur] ready; prev readers of buf[nxt] done
    const int nxt = cur ^ 1;
    if (k0 + BK2 < DIM) {
      const int koff = k0 + BK2;
      const int dsh = nxt ? 16384 : 0;
#pragma unroll
      for (int l = 0; l < 4; ++l)
        __builtin_amdgcn_global_load_lds(asrc[l] + koff, adst[l] + dsh, 16, 0, 0);
#pragma unroll
      for (int l = 0; l < 4; ++l)
        __builtin_amdgcn_global_load_lds(bsrc[l] + koff, bdst[l] + dsh, 16, 0, 0);
    }
    const char* Ab = (const char*)smem + 1024 + (cur ? 32768 : 0);
    const char* Bb = Ab + 16384;
#pragma unroll
    for (int ks = 0; ks < 2; ++ks) {
      const int kb = ks * 64 + hi * 16;
      bf16x8 af[4], bfr[4];
#pragma unroll
      for (int mi = 0; mi < 4; ++mi) {
        int r = wr * 64 + mi * 16 + lr;
        af[mi] = *(const bf16x8*)(Ab + r * 128 + (kb ^ ((r & 7) << 4)));
      }
#pragma unroll
      for (int ni = 0; ni < 4; ++ni) {
        int n = wc * 64 + ni * 16 + lr;
        bfr[ni] = *(const bf16x8*)(Bb + n * 128 + (kb ^ ((n & 7) << 4)));
      }
#pragma unroll
      for (int mi = 0; mi < 4; ++mi)
#pragma unroll
        for (int ni = 0; ni < 4; ++ni)
          acc[mi][ni] = __builtin_amdgcn_mfma_f32_16x16x32_bf16(
              af[mi], bfr[ni], acc[mi][ni], 0, 0, 0);
    }
    cur = nxt;
  }
  __syncthreads();

  // ---- epilogue: gate+bias in fp32, bf16 LDS transpose, uint4 stores ----
  ushort (*Ep)[72] = (ushort(*)[72])(smem + 1024 + w * 9216);  // [64][72]
  float bcol[4];
#pragma unroll
  for (int ni = 0; ni < 4; ++ni)
    bcol[ni] = be[(size_t)e * DOUT + c0 + wc * 64 + ni * 16 + lr];
#pragma unroll
  for (int mi = 0; mi < 4; ++mi)
#pragma unroll
    for (int r = 0; r < 4; ++r) {
      int rowl = mi * 16 + hi * 4 + r;      // C/D: col=lane&15, row=(lane>>4)*4+reg
      float g = sgate[wr * 64 + rowl];
#pragma unroll
      for (int ni = 0; ni < 4; ++ni)
        Ep[rowl][ni * 16 + lr] = f2b(g * (acc[mi][ni][r] + bcol[ni]));
    }
  __syncthreads();
#pragma unroll
  for (int it = 0; it < 8; ++it) {
    int rowl = it * 8 + (lane >> 3);
    int slotL = wr * 64 + rowl;
    if (slotL < cnt) {
      uint4 v = *(const uint4*)&Ep[rowl][(lane & 7) * 8];
      *(uint4*)(contrib + (size_t)(rs + slotL) * DOUT + c0 + wc * 64 + (lane & 7) * 8) = v;
    }
  }
}

// --------- reduce: y[n] = contrib[inv[2n]] + contrib[inv[2n+1]] --------------
__global__ __launch_bounds__(256) void k_reduce(
    const ushort* __restrict__ contrib, const int* __restrict__ inv,
    float* __restrict__ y) {
  const int t = threadIdx.x;
  const int n = blockIdx.x * 2 + (t >> 7);
  const int c = (t & 127) * 8;
  const int p0 = inv[2 * n], p1 = inv[2 * n + 1];
  uint4 a = *(const uint4*)(contrib + (size_t)p0 * DOUT + c);
  uint4 b = *(const uint4*)(contrib + (size_t)p1 * DOUT + c);
  const ushort* ua = (const ushort*)&a;
  const ushort* ub = (const ushort*)&b;
  float4 o0, o1;
  o0.x = b2f(ua[0]) + b2f(ub[0]);
  o0.y = b2f(ua[1]) + b2f(ub[1]);
  o0.z = b2f(ua[2]) + b2f(ub[2]);
  o0.w = b2f(ua[3]) + b2f(ub[3]);
  o1.x = b2f(ua[4]) + b2f(ub[4]);
  o1.y = b2f(ua[5]) + b2f(ub[5]);
  o1.z = b2f(ua[6]) + b2f(ub[6]);
  o1.w = b2f(ua[7]) + b2f(ub[7]);
  float* yr = y + (size_t)n * DOUT + c;
  *(float4*)yr = o0;
  *(float4*)(yr + 4) = o1;
}

extern "C" void kernel_launch(void* const* d_in, const int* in_sizes, int n_in,
                              void* d_out, int out_size, void* d_ws, size_t ws_size,
                              hipStream_t stream) {
  (void)in_sizes; (void)n_in; (void)ws_size; (void)out_size;
  const float* x   = (const float*)d_in[0];
  const float* wg1 = (const float*)d_in[1];
  const float* bg1 = (const float*)d_in[2];
  const float* wg2 = (const float*)d_in[3];
  const float* bg2 = (const float*)d_in[4];
  const float* We  = (const float*)d_in[5];
  const float* be  = (const float*)d_in[6];
  float* y = (float*)d_out;

  char* ws = (char*)d_ws;
  float*  h       = (float*)ws;                                      // 8 MB
  ushort* xb      = (ushort*)(ws + (size_t)N_TOK * DHID * 4);        // 16 MB
  ushort* weT     = (ushort*)((char*)xb + (size_t)N_TOK * DIM * 2);  // 40 MB
  ushort* contrib = (ushort*)((char*)weT + (size_t)NE * DIM * DOUT * 2);  // 32 MB
  char*   ctrl    = (char*)contrib + (size_t)2 * N_TOK * DOUT * 2;
  int*   counts  = (int*)ctrl;
  int*   zcur    = counts + 64;                  // zeroed in k_front (bid 7679)
  int*   tokexp  = counts + 128;
  float* tokgate = (float*)(tokexp + 2 * N_TOK);
  int*   perm    = (int*)(tokgate + 2 * N_TOK);
  float* pgate   = (float*)(perm + 2 * N_TOK);
  int*   inv     = (int*)(pgate + 2 * N_TOK);

  k_front<<<dim3(512 + 5120 + 2048), 256, 0, stream>>>(x, wg1, bg1, h, We, weT, xb, counts);
  k_router<<<dim3(N_TOK / 64), 64, 0, stream>>>(h, wg2, bg2, tokexp, tokgate, counts);
  k_scatter<<<dim3(N_TOK / 256), 256, 0, stream>>>(tokexp, tokgate, counts, zcur,
                                                   perm, pgate, inv);
  k_expert<<<dim3(MAX_TT, DOUT / BN2), 256, 0, stream>>>(
      xb, weT, be, perm, pgate, counts, contrib);
  k_reduce<<<dim3(N_TOK / 2), 256, 0, stream>>>(contrib, inv, y);
}

// Round 22
// 151.219 us; speedup vs baseline: 1.3366x; 1.1920x over previous
//
#include <hip/hip_runtime.h>
#include <hip/hip_bf16.h>
#include <math.h>

// MoE: B=4,S=2048 -> N=8192 tokens, D=1024, DO=1024, E=20 experts, top-2.
// R22: gate GEMM -> split-bf16 MFMA (x=hi+lo, w=hi+lo; 3 products hihi+hilo+
// lohi into fp32 acc; logit noise ~1.6e-5, est. flip risk ~3%). k_front is now
// pure memory (weT transpose, x->hi/lo, wg1->wg1T hi/lo). k_gate = expert-
// template clone (64x64 tile, 4 waves, dbuf, gload_lds + XOR swizzle).
// Router/scatter/expert/reduce identical to R21 (best, 180.2us).

#define N_TOK 8192
#define DIM   1024
#define DHID  256
#define DOUT  1024
#define NE    20
#define BM2   128
#define BN2   128
#define BK2   64
// sum_e ceil(cnt_e/128) <= 16384/128 + 20 = 148
#define MAX_TT 148

typedef __attribute__((ext_vector_type(8))) short bf16x8;
typedef __attribute__((ext_vector_type(4))) float f32x4;

__device__ __forceinline__ float gelu_erf(float v) {
    return 0.5f * v * (1.0f + erff(v * 0.70710678118654752f));
}

__device__ __forceinline__ ushort f2b(float f) {
  union { float f; uint u; } c; c.f = f;
  uint r = (c.u + 0x7FFFu + ((c.u >> 16) & 1u)) >> 16;  // RNE
  return (ushort)r;
}

__device__ __forceinline__ float b2f(ushort u) {
  union { uint u; float f; } c; c.u = ((uint)u) << 16;
  return c.f;
}

// ==== k_front: [0,5120) We->bf16T | [5120,7168) x->hi/lo | [7168,7232) wg1T
__global__ __launch_bounds__(256) void k_front(
    const float* __restrict__ x, const float* __restrict__ wg1,
    const float* __restrict__ We, ushort* __restrict__ weT,
    ushort* __restrict__ xb, ushort* __restrict__ xlo,
    ushort* __restrict__ w1h, ushort* __restrict__ w1l,
    int* __restrict__ counts) {
  __shared__ __align__(1024) char smem[16384];
  const int bid = blockIdx.x;
  const int t = threadIdx.x;

  if (bid < 5120) {
    // ---- We [e][k][n] fp32 -> weT [e][n][k] bf16 (conflict-free) ----
    ushort* Ts = (ushort*)smem;                            // 8192 B
    const int b = bid;
    const int e = b >> 8, rem = b & 255;
    const int k0 = (rem >> 4) * 64;
    const int n0 = (rem & 15) * 64;
    const float* src = We + ((size_t)e << 20);
    const int m = t & 15;
    const int xk = (m & 7) << 3;
#pragma unroll
    for (int it = 0; it < 4; ++it) {
      int kk = it * 16 + (t >> 4);
      int nn = m * 4;
      float4 v = *(const float4*)(src + (size_t)(k0 + kk) * DOUT + n0 + nn);
      int col = kk ^ xk;
      Ts[(nn + 0) * 64 + col] = f2b(v.x);
      Ts[(nn + 1) * 64 + col] = f2b(v.y);
      Ts[(nn + 2) * 64 + col] = f2b(v.z);
      Ts[(nn + 3) * 64 + col] = f2b(v.w);
    }
    __syncthreads();
    ushort* dst = weT + ((size_t)e << 20);
#pragma unroll
    for (int it = 0; it < 2; ++it) {
      int nn = it * 32 + (t >> 3);
      int ks = (t & 7) * 8;
      int cs = ks ^ (((nn >> 2) & 7) << 3);
      uint4 v = *(const uint4*)&Ts[nn * 64 + cs];
      *(uint4*)(dst + (size_t)(n0 + nn) * DIM + k0 + ks) = v;
    }
  } else if (bid < 7168) {
    // ---- x fp32 -> (hi, lo) bf16 pair, 16 elems/thread ----
    if (bid == 7167 && t < 128) counts[t] = 0;   // replaces hipMemsetAsync
    const size_t i0 = (((size_t)(bid - 5120)) * 256 + t) * 16;
    ushort oh[16], ol[16];
#pragma unroll
    for (int j = 0; j < 4; ++j) {
      float4 v = *(const float4*)(x + i0 + j * 4);
      const float* vf = (const float*)&v;
#pragma unroll
      for (int u = 0; u < 4; ++u) {
        ushort hu = f2b(vf[u]);
        oh[j * 4 + u] = hu;
        ol[j * 4 + u] = f2b(vf[u] - b2f(hu));
      }
    }
    *(uint4*)(xb + i0)      = *(const uint4*)&oh[0];
    *(uint4*)(xb + i0 + 8)  = *(const uint4*)&oh[8];
    *(uint4*)(xlo + i0)     = *(const uint4*)&ol[0];
    *(uint4*)(xlo + i0 + 8) = *(const uint4*)&ol[8];
  } else {
    // ---- wg1 [k=1024][n=256] fp32 -> wg1T hi/lo [n=256][k=1024] bf16 ----
    ushort* Th = (ushort*)smem;                 // 8192 B
    ushort* Tl = (ushort*)(smem + 8192);        // 8192 B
    const int b2 = bid - 7168;                  // 0..63
    const int k0 = (b2 >> 2) * 64;
    const int n0 = (b2 & 3) * 64;
    const int m = t & 15;
    const int xk = (m & 7) << 3;
#pragma unroll
    for (int it = 0; it < 4; ++it) {
      int kk = it * 16 + (t >> 4);
      int nn = m * 4;
      float4 v = *(const float4*)(wg1 + (size_t)(k0 + kk) * DHID + n0 + nn);
      const float* vf = (const float*)&v;
      int col = kk ^ xk;
#pragma unroll
      for (int u = 0; u < 4; ++u) {
        ushort hu = f2b(vf[u]);
        Th[(nn + u) * 64 + col] = hu;
        Tl[(nn + u) * 64 + col] = f2b(vf[u] - b2f(hu));
      }
    }
    __syncthreads();
#pragma unroll
    for (int it = 0; it < 2; ++it) {
      int nn = it * 32 + (t >> 3);
      int ks = (t & 7) * 8;
      int cs = ks ^ (((nn >> 2) & 7) << 3);
      uint4 vh = *(const uint4*)&Th[nn * 64 + cs];
      uint4 vl = *(const uint4*)&Tl[nn * 64 + cs];
      *(uint4*)(w1h + (size_t)(n0 + nn) * DIM + k0 + ks) = vh;
      *(uint4*)(w1l + (size_t)(n0 + nn) * DIM + k0 + ks) = vl;
    }
  }
}

// ---- k_gate: h = gelu(x @ wg1 + bg1) via split-bf16 MFMA -------------------
// 64x64 tile, 4 waves (2x2, wave-tile 32x32), BK=64, dbuf 64KB LDS.
// acc += Ah*Bh + Ah*Bl + Al*Bh  (fp32 MFMA accumulation).
__global__ __launch_bounds__(256) void k_gate(
    const ushort* __restrict__ xb, const ushort* __restrict__ xlo,
    const ushort* __restrict__ w1h, const ushort* __restrict__ w1l,
    const float* __restrict__ bg1, float* __restrict__ h) {
  // buf0: Ah@0 Al@8192 Bh@16384 Bl@24576 | buf1 at +32768
  __shared__ __align__(1024) char smem[65536];
  const int t = threadIdx.x;
  const int m0 = blockIdx.x * 64;
  const int c0 = blockIdx.y * 64;
  const int lane = t & 63, w = t >> 6;
  const int wr = w >> 1, wc = w & 1;          // 2x2 wave grid
  const int lr = lane & 15, hi = lane >> 4;

  const ushort* gsrc[8];
  ushort* gdst[8];
  {
    const ushort* mats[4] = {xb, xlo, w1h, w1l};
#pragma unroll
    for (int m = 0; m < 4; ++m) {
      int rbase = (m < 2) ? m0 : c0;
#pragma unroll
      for (int l = 0; l < 2; ++l) {
        int i = t + l * 256;
        int row = i >> 3, seg = i & 7;
        gsrc[m * 2 + l] = mats[m] + (size_t)(rbase + row) * DIM +
                          ((seg ^ (row & 7)) << 3);
        gdst[m * 2 + l] = (ushort*)smem + m * 4096 + i * 8;
      }
    }
  }

  f32x4 acc[2][2] = {};

  // prologue: stage k=0 into buf0
#pragma unroll
  for (int j = 0; j < 8; ++j)
    __builtin_amdgcn_global_load_lds(gsrc[j], gdst[j], 16, 0, 0);

  int cur = 0;
  for (int k0 = 0; k0 < DIM; k0 += 64) {
    __syncthreads();   // buf[cur] staged; prev readers of buf[nxt] done
    if (k0 + 64 < DIM) {
      const int koff = k0 + 64;
      const int dsh = (cur ^ 1) ? 16384 : 0;   // ushort offset (32 KB)
#pragma unroll
      for (int j = 0; j < 8; ++j)
        __builtin_amdgcn_global_load_lds(gsrc[j] + koff, gdst[j] + dsh, 16, 0, 0);
    }
    const char* base = smem + (cur ? 32768 : 0);
    const char* Ah = base;
    const char* Al = base + 8192;
    const char* Bh = base + 16384;
    const char* Bl = base + 24576;
#pragma unroll
    for (int ks = 0; ks < 2; ++ks) {
      const int kb = ks * 64 + hi * 16;
      bf16x8 ah[2], al[2], bh[2], bl[2];
#pragma unroll
      for (int mi = 0; mi < 2; ++mi) {
        int r = wr * 32 + mi * 16 + lr;
        int off = r * 128 + (kb ^ ((r & 7) << 4));
        ah[mi] = *(const bf16x8*)(Ah + off);
        al[mi] = *(const bf16x8*)(Al + off);
      }
#pragma unroll
      for (int ni = 0; ni < 2; ++ni) {
        int n = wc * 32 + ni * 16 + lr;
        int off = n * 128 + (kb ^ ((n & 7) << 4));
        bh[ni] = *(const bf16x8*)(Bh + off);
        bl[ni] = *(const bf16x8*)(Bl + off);
      }
#pragma unroll
      for (int mi = 0; mi < 2; ++mi)
#pragma unroll
        for (int ni = 0; ni < 2; ++ni) {
          acc[mi][ni] = __builtin_amdgcn_mfma_f32_16x16x32_bf16(
              ah[mi], bh[ni], acc[mi][ni], 0, 0, 0);
          acc[mi][ni] = __builtin_amdgcn_mfma_f32_16x16x32_bf16(
              ah[mi], bl[ni], acc[mi][ni], 0, 0, 0);
          acc[mi][ni] = __builtin_amdgcn_mfma_f32_16x16x32_bf16(
              al[mi], bh[ni], acc[mi][ni], 0, 0, 0);
        }
    }
    cur ^= 1;
  }

  // ---- epilogue: bias + gelu, scalar stores (lanes 0-15 coalesce 64B) ----
  float bcol[2];
#pragma unroll
  for (int ni = 0; ni < 2; ++ni)
    bcol[ni] = bg1[c0 + wc * 32 + ni * 16 + lr];
#pragma unroll
  for (int mi = 0; mi < 2; ++mi)
#pragma unroll
    for (int r = 0; r < 4; ++r) {
      int row = m0 + wr * 32 + mi * 16 + hi * 4 + r;  // C/D: col=lane&15, row=(lane>>4)*4+reg
#pragma unroll
      for (int ni = 0; ni < 2; ++ni) {
        int col = c0 + wc * 32 + ni * 16 + lr;
        h[(size_t)row * DHID + col] = gelu_erf(acc[mi][ni][r] + bcol[ni]);
      }
    }
}

// -------- router: logits = (h@wg2+bg2)[:, :20], softmax, top-2, counts -------
// 128 blocks x 64 threads; float4 swg reads; per-block LDS histogram.
__global__ __launch_bounds__(64) void k_router(
    const float* __restrict__ h, const float* __restrict__ wg2,
    const float* __restrict__ bg2, int* __restrict__ tokexp,
    float* __restrict__ tokgate, int* __restrict__ counts) {
  __shared__ float swg[DHID * NE];   // 20 KB
  __shared__ int hist[NE];
  const int t = threadIdx.x;
  if (t < NE) hist[t] = 0;
  for (int i = t; i < DHID * NE; i += 64) {
    int k = i / NE, j = i - k * NE;
    swg[i] = wg2[(size_t)k * (2 * NE) + j];
  }
  __syncthreads();
  const int n = blockIdx.x * 64 + t;
  float s[NE];
#pragma unroll
  for (int j = 0; j < NE; ++j) s[j] = bg2[j];
  const float* hr = h + (size_t)n * DHID;
  for (int k = 0; k < DHID; k += 4) {
    float4 hv = *(const float4*)(hr + k);
#pragma unroll
    for (int u = 0; u < 4; ++u) {
      float hvu = reinterpret_cast<const float*>(&hv)[u];
      const float4* wrow = (const float4*)&swg[(k + u) * NE];
      float wl[NE];
      *(float4*)&wl[0]  = wrow[0];
      *(float4*)&wl[4]  = wrow[1];
      *(float4*)&wl[8]  = wrow[2];
      *(float4*)&wl[12] = wrow[3];
      *(float4*)&wl[16] = wrow[4];
#pragma unroll
      for (int j = 0; j < NE; ++j) s[j] += hvu * wl[j];
    }
  }
  float m = s[0];
#pragma unroll
  for (int j = 1; j < NE; ++j) m = fmaxf(m, s[j]);
  float sum = 0.0f;
#pragma unroll
  for (int j = 0; j < NE; ++j) { s[j] = expf(s[j] - m); sum += s[j]; }
  float inv = 1.0f / sum;
#pragma unroll
  for (int j = 0; j < NE; ++j) s[j] *= inv;
  int j0 = 0; float v0 = s[0];
#pragma unroll
  for (int j = 1; j < NE; ++j) if (s[j] > v0) { v0 = s[j]; j0 = j; }
  int j1 = -1; float v1 = -1.0f;
#pragma unroll
  for (int j = 0; j < NE; ++j)
    if (j != j0 && s[j] > v1) { v1 = s[j]; j1 = j; }
  tokexp[2 * n + 0] = j0;  tokgate[2 * n + 0] = v0;
  tokexp[2 * n + 1] = j1;  tokgate[2 * n + 1] = v1;
  atomicAdd(&hist[j0], 1);
  atomicAdd(&hist[j1], 1);
  __syncthreads();
  if (t < NE) atomicAdd(&counts[t], hist[t]);
}

// ------ scatter: LDS-aggregated cursor claim ---------------------------------
__global__ __launch_bounds__(256) void k_scatter(
    const int* __restrict__ tokexp, const float* __restrict__ tokgate,
    const int* __restrict__ counts, int* __restrict__ zcur,
    int* __restrict__ perm, float* __restrict__ pgate, int* __restrict__ inv) {
  __shared__ int soff[NE], lcnt[NE], lbase[NE];
  const int t = threadIdx.x;
  if (t < NE) lcnt[t] = 0;
  if (t < 64) {
    int c = (t < NE) ? counts[t] : 0;
    int cs = c;
    for (int d = 1; d < 64; d <<= 1) {
      int u = __shfl_up(cs, d); if (t >= d) cs += u;
    }
    if (t < NE) soff[t] = cs - c;
  }
  __syncthreads();
  const int n = blockIdx.x * 256 + t;
  const int e0 = tokexp[2 * n + 0];
  const int e1 = tokexp[2 * n + 1];
  const int r0 = atomicAdd(&lcnt[e0], 1);
  const int r1 = atomicAdd(&lcnt[e1], 1);
  __syncthreads();
  if (t < NE) lbase[t] = atomicAdd(&zcur[t], lcnt[t]);
  __syncthreads();
  {
    int pos = soff[e0] + lbase[e0] + r0;
    perm[pos] = n;
    pgate[pos] = tokgate[2 * n + 0];
    inv[2 * n + 0] = pos;
  }
  {
    int pos = soff[e1] + lbase[e1] + r1;
    perm[pos] = n;
    pgate[pos] = tokgate[2 * n + 1];
    inv[2 * n + 1] = pos;
  }
}

// ------ grouped expert GEMM (bf16 MFMA): contrib[pos] = g*(x@We[e]+be[e]) ----
// 128x128 tile, BK=64, 2-phase double-buffered LDS. In-block prefix.
__global__ __launch_bounds__(256) void k_expert(
    const ushort* __restrict__ xb, const ushort* __restrict__ weT,
    const float* __restrict__ be, const int* __restrict__ perm,
    const float* __restrict__ pgate, const int* __restrict__ counts,
    ushort* __restrict__ contrib) {
  // XCD-chunked swizzle: 1184 blocks = 8 XCDs x 148
  const int lin = blockIdx.x + blockIdx.y * MAX_TT;
  const int nt8 = (lin & 7) * MAX_TT + (lin >> 3);
  const int rt = nt8 >> 3, pn = nt8 & 7;

  __shared__ __align__(1024) char smem[66560];
  int*    stok  = (int*)smem;
  float*  sgate = (float*)(smem + 512);
  ushort* As0   = (ushort*)(smem + 1024);
  ushort* Bs0   = (ushort*)(smem + 17408);
  __shared__ int tinfo[3];

  const int t = threadIdx.x;
  if (t < 64) {
    if (t == 0) tinfo[0] = -1;
    int c = (t < NE) ? counts[t] : 0;
    int nt = (c + BM2 - 1) >> 7;
    int cs = c, ts = nt;
    for (int d = 1; d < 64; d <<= 1) {
      int u = __shfl_up(cs, d); if (t >= d) cs += u;
      int v = __shfl_up(ts, d); if (t >= d) ts += v;
    }
    int coff = cs - c, toff = ts - nt;
    if (t < NE && rt >= toff && rt < toff + nt) {
      int i = rt - toff;
      tinfo[0] = t;
      tinfo[1] = coff + i * BM2;
      tinfo[2] = min(BM2, c - i * BM2);
    }
  }
  __syncthreads();
  if (tinfo[0] < 0) return;
  const int e = tinfo[0], rs = tinfo[1], cnt = tinfo[2];
  const int c0 = pn * BN2;

  if (t < BM2) {
    int r = (t < cnt) ? rs + t : rs;
    stok[t]  = perm[r];
    sgate[t] = (t < cnt) ? pgate[rs + t] : 0.0f;
  }
  __syncthreads();
  const int lane = t & 63, w = t >> 6;
  const int wr = w >> 1, wc = w & 1;
  const int lr = lane & 15, hi = lane >> 4;
  const int srow = lane >> 3, sseg = lane & 7;

  const ushort* asrc[4];
  const ushort* bsrc[4];
  ushort* adst[4];
  ushort* bdst[4];
#pragma unroll
  for (int l = 0; l < 4; ++l) {
    int r = w * 32 + l * 8 + srow;                    // 0..127
    asrc[l] = xb + (size_t)stok[r] * DIM + ((sseg ^ (r & 7)) << 3);
    adst[l] = As0 + (w * 32 + l * 8) * BK2;
    bsrc[l] = weT + ((size_t)e << 20) + (size_t)(c0 + r) * DIM + ((sseg ^ (r & 7)) << 3);
    bdst[l] = Bs0 + (w * 32 + l * 8) * BK2;
  }

  f32x4 acc[4][4] = {};

  // prologue: stage k=0 into buf0
#pragma unroll
  for (int l = 0; l < 4; ++l)
    __builtin_amdgcn_global_load_lds(asrc[l], adst[l], 16, 0, 0);
#pragma unroll
  for (int l = 0; l < 4; ++l)
    __builtin_amdgcn_global_load_lds(bsrc[l], bdst[l], 16, 0, 0);

  int cur = 0;
  for (int k0 = 0; k0 < DIM; k0 += BK2) {
    __syncthreads();   // buf[cur] ready; prev readers of buf[nxt] done
    const int nxt = cur ^ 1;
    if (k0 + BK2 < DIM) {
      const int koff = k0 + BK2;
      const int dsh = nxt ? 16384 : 0;
#pragma unroll
      for (int l = 0; l < 4; ++l)
        __builtin_amdgcn_global_load_lds(asrc[l] + koff, adst[l] + dsh, 16, 0, 0);
#pragma unroll
      for (int l = 0; l < 4; ++l)
        __builtin_amdgcn_global_load_lds(bsrc[l] + koff, bdst[l] + dsh, 16, 0, 0);
    }
    const char* Ab = (const char*)smem + 1024 + (cur ? 32768 : 0);
    const char* Bb = Ab + 16384;
#pragma unroll
    for (int ks = 0; ks < 2; ++ks) {
      const int kb = ks * 64 + hi * 16;
      bf16x8 af[4], bfr[4];
#pragma unroll
      for (int mi = 0; mi < 4; ++mi) {
        int r = wr * 64 + mi * 16 + lr;
        af[mi] = *(const bf16x8*)(Ab + r * 128 + (kb ^ ((r & 7) << 4)));
      }
#pragma unroll
      for (int ni = 0; ni < 4; ++ni) {
        int n = wc * 64 + ni * 16 + lr;
        bfr[ni] = *(const bf16x8*)(Bb + n * 128 + (kb ^ ((n & 7) << 4)));
      }
#pragma unroll
      for (int mi = 0; mi < 4; ++mi)
#pragma unroll
        for (int ni = 0; ni < 4; ++ni)
          acc[mi][ni] = __builtin_amdgcn_mfma_f32_16x16x32_bf16(
              af[mi], bfr[ni], acc[mi][ni], 0, 0, 0);
    }
    cur = nxt;
  }
  __syncthreads();

  // ---- epilogue: gate+bias in fp32, bf16 LDS transpose, uint4 stores ----
  ushort (*Ep)[72] = (ushort(*)[72])(smem + 1024 + w * 9216);  // [64][72]
  float bcol[4];
#pragma unroll
  for (int ni = 0; ni < 4; ++ni)
    bcol[ni] = be[(size_t)e * DOUT + c0 + wc * 64 + ni * 16 + lr];
#pragma unroll
  for (int mi = 0; mi < 4; ++mi)
#pragma unroll
    for (int r = 0; r < 4; ++r) {
      int rowl = mi * 16 + hi * 4 + r;      // C/D: col=lane&15, row=(lane>>4)*4+reg
      float g = sgate[wr * 64 + rowl];
#pragma unroll
      for (int ni = 0; ni < 4; ++ni)
        Ep[rowl][ni * 16 + lr] = f2b(g * (acc[mi][ni][r] + bcol[ni]));
    }
  __syncthreads();
#pragma unroll
  for (int it = 0; it < 8; ++it) {
    int rowl = it * 8 + (lane >> 3);
    int slotL = wr * 64 + rowl;
    if (slotL < cnt) {
      uint4 v = *(const uint4*)&Ep[rowl][(lane & 7) * 8];
      *(uint4*)(contrib + (size_t)(rs + slotL) * DOUT + c0 + wc * 64 + (lane & 7) * 8) = v;
    }
  }
}

// --------- reduce: y[n] = contrib[inv[2n]] + contrib[inv[2n+1]] --------------
__global__ __launch_bounds__(256) void k_reduce(
    const ushort* __restrict__ contrib, const int* __restrict__ inv,
    float* __restrict__ y) {
  const int t = threadIdx.x;
  const int n = blockIdx.x * 2 + (t >> 7);
  const int c = (t & 127) * 8;
  const int p0 = inv[2 * n], p1 = inv[2 * n + 1];
  uint4 a = *(const uint4*)(contrib + (size_t)p0 * DOUT + c);
  uint4 b = *(const uint4*)(contrib + (size_t)p1 * DOUT + c);
  const ushort* ua = (const ushort*)&a;
  const ushort* ub = (const ushort*)&b;
  float4 o0, o1;
  o0.x = b2f(ua[0]) + b2f(ub[0]);
  o0.y = b2f(ua[1]) + b2f(ub[1]);
  o0.z = b2f(ua[2]) + b2f(ub[2]);
  o0.w = b2f(ua[3]) + b2f(ub[3]);
  o1.x = b2f(ua[4]) + b2f(ub[4]);
  o1.y = b2f(ua[5]) + b2f(ub[5]);
  o1.z = b2f(ua[6]) + b2f(ub[6]);
  o1.w = b2f(ua[7]) + b2f(ub[7]);
  float* yr = y + (size_t)n * DOUT + c;
  *(float4*)yr = o0;
  *(float4*)(yr + 4) = o1;
}

extern "C" void kernel_launch(void* const* d_in, const int* in_sizes, int n_in,
                              void* d_out, int out_size, void* d_ws, size_t ws_size,
                              hipStream_t stream) {
  (void)in_sizes; (void)n_in; (void)ws_size; (void)out_size;
  const float* x   = (const float*)d_in[0];
  const float* wg1 = (const float*)d_in[1];
  const float* bg1 = (const float*)d_in[2];
  const float* wg2 = (const float*)d_in[3];
  const float* bg2 = (const float*)d_in[4];
  const float* We  = (const float*)d_in[5];
  const float* be  = (const float*)d_in[6];
  float* y = (float*)d_out;

  char* ws = (char*)d_ws;
  float*  h       = (float*)ws;                                       // 8 MB
  ushort* xb      = (ushort*)(ws + (size_t)N_TOK * DHID * 4);         // 16 MB
  ushort* xlo     = (ushort*)((char*)xb + (size_t)N_TOK * DIM * 2);   // 16 MB
  ushort* weT     = (ushort*)((char*)xlo + (size_t)N_TOK * DIM * 2);  // 40 MB
  ushort* w1h     = (ushort*)((char*)weT + (size_t)NE * DIM * DOUT * 2);  // 0.5 MB
  ushort* w1l     = w1h + (size_t)DHID * DIM;                          // 0.5 MB
  ushort* contrib = w1l + (size_t)DHID * DIM;                          // 32 MB
  char*   ctrl    = (char*)contrib + (size_t)2 * N_TOK * DOUT * 2;
  int*   counts  = (int*)ctrl;
  int*   zcur    = counts + 64;                  // zeroed in k_front (bid 7167)
  int*   tokexp  = counts + 128;
  float* tokgate = (float*)(tokexp + 2 * N_TOK);
  int*   perm    = (int*)(tokgate + 2 * N_TOK);
  float* pgate   = (float*)(perm + 2 * N_TOK);
  int*   inv     = (int*)(pgate + 2 * N_TOK);

  k_front<<<dim3(5120 + 2048 + 64), 256, 0, stream>>>(
      x, wg1, We, weT, xb, xlo, w1h, w1l, counts);
  k_gate<<<dim3(N_TOK / 64, DHID / 64), 256, 0, stream>>>(
      xb, xlo, w1h, w1l, bg1, h);
  k_router<<<dim3(N_TOK / 64), 64, 0, stream>>>(h, wg2, bg2, tokexp, tokgate, counts);
  k_scatter<<<dim3(N_TOK / 256), 256, 0, stream>>>(tokexp, tokgate, counts, zcur,
                                                   perm, pgate, inv);
  k_expert<<<dim3(MAX_TT, DOUT / BN2), 256, 0, stream>>>(
      xb, weT, be, perm, pgate, counts, contrib);
  k_reduce<<<dim3(N_TOK / 2), 256, 0, stream>>>(contrib, inv, y);
}